// Round 15
// baseline (342.075 us; speedup 1.0000x reference)
//
#include <hip/hip_runtime.h>
#include <cstdint>

typedef unsigned short u16;
typedef unsigned int   u32;
typedef float  f32x4  __attribute__((ext_vector_type(4)));
typedef short  short8 __attribute__((ext_vector_type(8)));

__device__ inline float bf2f(u16 b){ u32 u=((u32)b)<<16; float f; __builtin_memcpy(&f,&u,4); return f; }
__device__ inline u16 f2bf(float f){ u32 u; __builtin_memcpy(&u,&f,4); u32 r=u+0x7FFFu+((u>>16)&1u); return (u16)(r>>16); }
__device__ inline float ubits(u32 u){ float f; __builtin_memcpy(&f,&u,4); return f; }
// truncating pack (1 op; exact when inputs already bf16-valued)
__device__ inline u32 pk(float hi, float lo){ u32 a,b; __builtin_memcpy(&a,&hi,4); __builtin_memcpy(&b,&lo,4); return __builtin_amdgcn_perm(a,b,0x07060302u); }
// RNE pack via HW (r13-validated bit-exact)
__device__ inline u32 cvtpk(float lo, float hi){ u32 r; asm("v_cvt_pk_bf16_f32 %0, %1, %2" : "=v"(r) : "v"(lo), "v"(hi)); return r; }
__device__ inline void gload_lds16(const void* g, void* l){
  __builtin_amdgcn_global_load_lds((const __attribute__((address_space(1))) unsigned int*)g,
                                   (__attribute__((address_space(3))) unsigned int*)l, 16, 0, 0);
}

// counted-vmcnt barrier (T4)
#define CBAR(K) do{ asm volatile("s_waitcnt vmcnt(" #K ") lgkmcnt(0)" ::: "memory"); \
  __builtin_amdgcn_s_barrier(); __builtin_amdgcn_sched_barrier(0); }while(0)

// ---------------------------------------------------------------------------
// prep (unchanged — staged-order weight images):
//  tile t (of 16, 32 k each) = 16384 u16 = 256 lines x 128B.
//  decode of u16 offset o: line=o>>6, w=o&63, slot=w>>3, i=w&7,
//    c8 = slot ^ (line&7), n = 2*line + (c8>>2), g = c8&3.
//  Wt_in3 value = bf16(W_in[k][n]),  k = t*32 + g*8 + i      (linear k)
//  Wt_hd3 value = bf16(W_head[k][n]), k = t*32 + sigma(g,i)  (sigma-permuted)
//  gw1f: S-MFMA B-frags [8d][16c][4g][5col][8i] (2560/depth)
//  updA: update A-frags [8d][32t][16m][8sl]     (4096/depth)
// ---------------------------------------------------------------------------
__global__ __launch_bounds__(256) void prep_k(
    const float* __restrict__ W_in, const float* __restrict__ W_head,
    const float* __restrict__ ln_g, const float* __restrict__ W1,
    const float* __restrict__ W2, const float* __restrict__ b2,
    u16* __restrict__ Wt_in3, u16* __restrict__ Wt_hd3,
    u16* __restrict__ gw1f, u16* __restrict__ updA)
{
  int idx = blockIdx.x * 256 + threadIdx.x;
  if (idx < 524288){
    int which = idx >> 18;            // 0: W_in, 1: W_head
    int q = idx & 262143;
    int t = q >> 14, o = q & 16383;
    int line = o >> 6, w = o & 63, slot = w >> 3, i = w & 7;
    int c8 = slot ^ (line & 7);
    int n = 2 * line + (c8 >> 2);
    int g = c8 & 3;
    if (which == 0){
      int k = t * 32 + g * 8 + i;
      Wt_in3[q] = f2bf(W_in[k * 512 + n]);
    } else {
      int k = t * 32 + (i < 4 ? 4 * g + i : 12 + 4 * g + i);
      Wt_hd3[q] = f2bf(W_head[k * 512 + n]);
    }
  } else if (idx < 544768){
    int q = idx - 524288;                 // 8*2560
    int d = q / 2560, r = q % 2560;
    int c = r / 160, r2 = r % 160;
    int g = r2 / 40, r3 = r2 % 40;
    int col = r3 >> 3, i = r3 & 7;
    int k = 32 * c + (i < 4 ? 4 * g + i : 12 + 4 * g + i);
    u16 v;
    if (col == 4) v = 0x3F80u;
    else          v = f2bf(ln_g[d * 512 + k] * W1[(d * 512 + k) * 4 + col]);
    gw1f[q] = v;
  } else if (idx < 577536){
    int q = idx - 544768;                 // 8*4096
    int d = q >> 12, r = q & 4095;
    int t = r >> 7, r2 = r & 127;
    int m = r2 >> 3, sl = r2 & 7;
    int k = 16 * t + m;
    u16 v = 0;
    if (sl < 4)       v = f2bf(W2[(d * 4 + sl) * 512 + k]);
    else if (sl == 4) v = f2bf(b2[d * 512 + k]);
    updA[q] = v;
  }
}

// U[d][e] = sum_k bf16(g*W1); V = sum ln_b*W1 + b1
__global__ __launch_bounds__(64) void uv_k(
    const float* __restrict__ ln_g, const float* __restrict__ ln_b,
    const float* __restrict__ W1, const float* __restrict__ b1,
    float* __restrict__ U, float* __restrict__ V)
{
  int d = blockIdx.x >> 2, e = blockIdx.x & 3;
  int lane = threadIdx.x;
  float u = 0.f, v = 0.f;
  for (int k = lane; k < 512; k += 64){
    float w = W1[(d * 512 + k) * 4 + e];
    u += bf2f(f2bf(ln_g[d * 512 + k] * w));
    v += ln_b[d * 512 + k] * w;
  }
  for (int m = 1; m < 64; m <<= 1){ u += __shfl_xor(u, m); v += __shfl_xor(v, m); }
  if (lane == 0){ U[d * 4 + e] = u; V[d * 4 + e] = v + b1[d * 4 + e]; }
}

// ---------------------------------------------------------------------------
// fused v10: r14 + (1) phase A at BK=64 (8 bodies, 4-slot/2-pair LDS rotation,
// CBAR(16)), (2) mid at 2 barriers/depth (stage moved after the sSf CBAR(0)),
// (3) phase C remapped to the 4-slot rotation (logic unchanged).
// LDS map (LT = 147728; overlays temporally disjoint, race-audited):
//   [0,131072)       4 x 32K weight-tile slots (A: pairs in slots {0,1}/{2,3};
//                    C: tile c in slot (c+2)&3)
//   [0,49152)        mid mbuf 3x16384 [mid only; A slots dead, barrier-guarded]
//   [49152,61440)    sS partials [mid only]
//   [61440,63488)    zbuf        [mid only]
//   [131072,147456)  hx h-broadcast 2x8192 [phase C only]
//   [147456,147728)  sUV + sZ (persistent)
// hv[q][c2][half][r] = h[row=rh*64+q*16+m][k=nq*128+c2*32+half*16+4g+r]
// ---------------------------------------------------------------------------
__global__ __launch_bounds__(512, 2) void fused_k(
    const float* __restrict__ x, const u16* __restrict__ Wt_in3,
    const float* __restrict__ b_in, const u16* __restrict__ Wt_hd3,
    const float* __restrict__ b_head, const u16* __restrict__ gw1f,
    const u16* __restrict__ updA, const float* __restrict__ U,
    const float* __restrict__ V, float* __restrict__ out)
{
  __shared__ __align__(16) char LT[147728];
  constexpr int MIDB = 0;        // mid mbuf base (3 x 16384)
  constexpr int SSo = 49152, ZBo = 61440;
  constexpr int HXo = 131072;
  constexpr int UVo = 147456, SZo = 147712;
  float* sSf = (float*)(LT + SSo);
  float* zbf = (float*)(LT + ZBo);
  float* sUV = (float*)(LT + UVo);
  u16*   sZ  = (u16*)(LT + SZo);

  const int tid  = threadIdx.x;
  const int wv   = tid >> 6;
  const int lane = tid & 63;
  const int m    = lane & 15;
  const int g    = lane >> 4;
  const int nq   = wv & 3;
  const int rh   = wv >> 2;
  const size_t rowbase = (size_t)blockIdx.x * 128 + rh * 64;

  if (tid < 32) sUV[tid] = U[tid];
  else if (tid < 64) sUV[tid] = V[tid - 32];
  if (tid >= 64 && tid < 72) sZ[tid - 64] = 0;

  // stage weight tile T into slot (4 loads/thread)
  auto stage4 = [&](const u16* W, int T, int slot){
    const char* src = (const char*)(W + T * 16384) + tid * 16;
    char* d2 = LT + slot * 32768 + tid * 16;
    #pragma unroll
    for (int j = 0; j < 4; ++j)
      gload_lds16(src + j * 8192, d2 + j * 8192);
  };
  auto stageM = [&](int d, int bf3){                   // 1-2 loads/thread
    char* dsg = LT + MIDB + bf3 * 16384;
    if (tid < 320)
      gload_lds16((const char*)gw1f + d * 5120 + tid * 16, dsg + tid * 16);
    gload_lds16((const char*)updA + d * 8192 + tid * 16, dsg + 5120 + tid * 16);
  };

  auto mkfrag = [&](f32x4 a, f32x4 b)->short8{     // RNE via v_cvt_pk
    union{u32 u[4]; short8 s;} t;
    t.u[0]=cvtpk(a[0],a[1]); t.u[1]=cvtpk(a[2],a[3]);
    t.u[2]=cvtpk(b[0],b[1]); t.u[3]=cvtpk(b[2],b[3]);
    return t.s;
  };
  auto mkfragT = [&](f32x4 a, f32x4 b)->short8{    // trunc (mid path)
    union{u32 u[4]; short8 s;} t;
    t.u[0]=pk(a[1],a[0]); t.u[1]=pk(a[3],a[2]);
    t.u[2]=pk(b[1],b[0]); t.u[3]=pk(b[3],b[2]);
    return t.s;
  };

  // A-frag byte base inside a staged tile (conflict-light pattern)
  const int afoff = (m >> 1) * 128 + (((((m & 1) << 2) | g) ^ ((m >> 1) & 7)) << 4);

  // ================= phase A: h = relu(x @ W_in + b_in), BK=64 ===========
  f32x4 hv[4][4][2];
  #pragma unroll
  for (int q = 0; q < 4; ++q)
    #pragma unroll
    for (int c2 = 0; c2 < 4; ++c2){ hv[q][c2][0] = (f32x4)0.f; hv[q][c2][1] = (f32x4)0.f; }

  const float* xbase = x + (rowbase + m) * 512 + g * 8;
  f32x4 xr[4][2][2];               // [q][chunk][half8] for current body
  #pragma unroll
  for (int q = 0; q < 4; ++q)
    #pragma unroll
    for (int ch = 0; ch < 2; ++ch){
      xr[q][ch][0] = *(const f32x4*)(xbase + q * 8192 + ch * 32);
      xr[q][ch][1] = *(const f32x4*)(xbase + q * 8192 + ch * 32 + 4);
    }
  stage4(Wt_in3, 0, 0);
  stage4(Wt_in3, 1, 1);
  CBAR(0);

  // Body t (0..7): stage pair t+1 (tiles 2t+2,2t+3) ; pack bq from xr ;
  // reload xr for body t+1 [16 loads] ; 64 MFMA on slots {2(t&1),2(t&1)+1} ;
  // CBAR(16) keeps x-prefetch, drains this body's stage (read next body).
  #pragma unroll
  for (int t = 0; t < 8; ++t){
    if (t < 7){
      stage4(Wt_in3, 2 * t + 2, (2 * t + 2) & 3);
      stage4(Wt_in3, 2 * t + 3, (2 * t + 3) & 3);
      __builtin_amdgcn_sched_barrier(0);   // pin: stage issues before x reloads
    }
    short8 bq[2][4];
    #pragma unroll
    for (int ch = 0; ch < 2; ++ch)
      #pragma unroll
      for (int q = 0; q < 4; ++q)
        bq[ch][q] = mkfrag(xr[q][ch][0], xr[q][ch][1]);
    if (t < 7){
      #pragma unroll
      for (int q = 0; q < 4; ++q)
        #pragma unroll
        for (int ch = 0; ch < 2; ++ch){
          xr[q][ch][0] = *(const f32x4*)(xbase + q * 8192 + (t + 1) * 64 + ch * 32);
          xr[q][ch][1] = *(const f32x4*)(xbase + q * 8192 + (t + 1) * 64 + ch * 32 + 4);
        }
    }
    #pragma unroll
    for (int ch = 0; ch < 2; ++ch){
      const char* wb = LT + ((2 * t + ch) & 3) * 32768 + nq * 8192 + afoff;
      #pragma unroll
      for (int f = 0; f < 8; ++f){
        short8 aw = *(const short8*)(wb + f * 1024);
        #pragma unroll
        for (int q = 0; q < 4; ++q)
          hv[q][f >> 1][f & 1] =
            __builtin_amdgcn_mfma_f32_16x16x32_bf16(aw, bq[ch][q], hv[q][f >> 1][f & 1], 0, 0, 0);
      }
    }
    if (t < 7) CBAR(16);
  }

  // epilogue: +bias, relu, RNE round to bf16 values
  #pragma unroll
  for (int q = 0; q < 4; ++q)
    #pragma unroll
    for (int c2 = 0; c2 < 4; ++c2)
      #pragma unroll
      for (int hf = 0; hf < 2; ++hf){
        f32x4 bi = *(const f32x4*)(b_in + nq * 128 + c2 * 32 + hf * 16 + g * 4);
        f32x4 v;
        #pragma unroll
        for (int r = 0; r < 4; ++r){ float w = hv[q][c2][hf][r] + bi[r]; v[r] = w > 0.f ? w : 0.f; }
        u32 ua = cvtpk(v[0], v[1]), ub = cvtpk(v[2], v[3]);
        hv[q][c2][hf][0] = ubits(ua << 16);
        hv[q][c2][hf][1] = ubits(ua & 0xFFFF0000u);
        hv[q][c2][hf][2] = ubits(ub << 16);
        hv[q][c2][hf][3] = ubits(ub & 0xFFFF0000u);
      }

  // mid prologue: all A reads done -> safe to overlay mbuf onto slots 0/1
  __syncthreads();
  stageM(0, 0);
  stageM(1, 1);
  CBAR(0);

  // ================= mid: 8 depths, 2 barriers each =======================
  // S ; sSf ; CBAR(0) [drains stage(d+1), publishes sSf] ; stage(d+2) ;
  // z ; CBAR(8) [publishes zbf, keeps stage] ; update.
  #pragma unroll 1
  for (int d = 0; d < 8; ++d){
    const u16* sGp = (const u16*)(LT + MIDB + (d % 3) * 16384);
    const u16* sAp = sGp + 2560;

    // ---- per-slice S + sum(ones col) + Gram(sumsq), 4 row-groups
    const u16* gb = (m < 5) ? (sGp + nq * 640 + g * 40 + m * 8) : sZ;
    const int gstep = (m < 5) ? 160 : 0;
    f32x4 aS[4], aG[4];
    #pragma unroll
    for (int q = 0; q < 4; ++q){ aS[q] = (f32x4)0.f; aG[q] = (f32x4)0.f; }
    #pragma unroll
    for (int c2 = 0; c2 < 4; ++c2){
      short8 bf = *(const short8*)(gb + c2 * gstep);
      #pragma unroll
      for (int q = 0; q < 4; ++q){
        short8 af = mkfragT(hv[q][c2][0], hv[q][c2][1]);
        aS[q] = __builtin_amdgcn_mfma_f32_16x16x32_bf16(af, bf, aS[q], 0, 0, 0);
        aG[q] = __builtin_amdgcn_mfma_f32_16x16x32_bf16(af, af, aG[q], 0, 0, 0);
      }
    }

    // ---- write per-slice partials: [rh][q][nq][e=0..5][16 batch]
    #pragma unroll
    for (int q = 0; q < 4; ++q){
      if (m < 5)
        *(f32x4*)(sSf + (((rh * 4 + q) * 4 + nq) * 6 + m) * 16 + 4 * g) = aS[q];
      if ((m >> 2) == g)
        sSf[(((rh * 4 + q) * 4 + nq) * 6 + 5) * 16 + m] = aG[q][m & 3];
    }
    CBAR(0);   // drains stage(d+1) (1 depth old); publishes sSf

    // stage two depths ahead (safe: this buffer's last readers were depth
    // d-1, all upstream of the barrier we just passed)
    if (d < 6)       stageM(d + 2, (d + 2) % 3);
    else if (d == 6) stage4(Wt_hd3, 0, 2);     // head tile 0 -> slot 2
    else             stage4(Wt_hd3, 1, 3);     // head tile 1 -> slot 3

    // ---- z for all 128 rows (threads 0..127)
    if (tid < 128){
      int rh2 = tid >> 6, rl = tid & 63, q2 = rl >> 4, b = rl & 15;
      float S0 = 0.f, S1 = 0.f, S2 = 0.f, S3 = 0.f, sm = 0.f, sq = 0.f;
      #pragma unroll
      for (int nn = 0; nn < 4; ++nn){
        const float* pp = sSf + (((rh2 * 4 + q2) * 4 + nn) * 6) * 16 + b;
        S0 += pp[0]; S1 += pp[16]; S2 += pp[32]; S3 += pp[48];
        sm += pp[64]; sq += pp[80];
      }
      float mu  = sm * (1.f / 512.f);
      float var = sq * (1.f / 512.f) - mu * mu;
      float rs  = rsqrtf(var + 1e-5f);
      f32x4 zz;
      float z0 = fmaf(rs, S0 - mu * sUV[d * 4 + 0], sUV[32 + d * 4 + 0]);
      float z1 = fmaf(rs, S1 - mu * sUV[d * 4 + 1], sUV[32 + d * 4 + 1]);
      float z2 = fmaf(rs, S2 - mu * sUV[d * 4 + 2], sUV[32 + d * 4 + 2]);
      float z3 = fmaf(rs, S3 - mu * sUV[d * 4 + 3], sUV[32 + d * 4 + 3]);
      zz[0] = z0 > 0.f ? z0 : 0.f;
      zz[1] = z1 > 0.f ? z1 : 0.f;
      zz[2] = z2 > 0.f ? z2 : 0.f;
      zz[3] = z3 > 0.f ? z3 : 0.f;
      *(f32x4*)(zbf + tid * 4) = zz;
    }
    CBAR(8);   // publishes zbf; keeps fresh stage in flight

    // ---- update: h += [W2|b2]^T [z|1] on own k-slice
    #pragma unroll
    for (int q = 0; q < 4; ++q){
      f32x4 z4 = *(const f32x4*)(zbf + (rh * 64 + q * 16 + m) * 4);
      union{u32 u[4]; short8 s;} bz;
      bz.u[0] = (g == 0) ? pk(z4[1], z4[0]) : 0u;
      bz.u[1] = (g == 0) ? pk(z4[3], z4[2]) : 0u;
      bz.u[2] = (g == 0) ? 0x00003F80u : 0u;
      bz.u[3] = 0u;
      const u16* ab = (g == 0) ? (sAp + nq * 1024 + m * 8) : sZ;
      const int ainc = (g == 0) ? 128 : 0;
      #pragma unroll
      for (int t2 = 0; t2 < 8; ++t2){
        short8 aw = *(const short8*)(ab + t2 * ainc);
        hv[q][t2 >> 1][t2 & 1] =
          __builtin_amdgcn_mfma_f32_16x16x32_bf16(aw, bz.s, hv[q][t2 >> 1][t2 & 1], 0, 0, 0);
      }
    }
    // no depth-end barrier: next depth's stage issues only after its CBAR(0)
  }

  // ================= phase C: out = h @ W_head + b_head ===================
  // pack h (RNE via cvt_pk — pipeline's final h rounding)
  short8 p[4][4];
  #pragma unroll
  for (int q = 0; q < 4; ++q)
    #pragma unroll
    for (int c2 = 0; c2 < 4; ++c2)
      p[q][c2] = mkfrag(hv[q][c2][0], hv[q][c2][1]);

  f32x4 acc[4][8];
  #pragma unroll
  for (int q = 0; q < 4; ++q)
    #pragma unroll
    for (int of = 0; of < 8; ++of) acc[q][of] = (f32x4)0.f;

  // prologue: broadcast chunk 0 (tiles 0,1 staged at mid d6/d7); full drain
  if (nq == 0){
    #pragma unroll
    for (int q = 0; q < 4; ++q)
      *(short8*)(LT + HXo + rh * 4096 + (q * 64 + m * 4 + g) * 16) = p[q][0];
  }
  CBAR(0);

  // Body c: stage tile c+2 -> slot c&3 ; hx-write c+1 (owner) ;
  // read slot (c+2)&3 + hx[c&1] ; CBAR(4) keeps fresh stage. c=14: CBAR(0).
  #pragma unroll
  for (int c = 0; c < 16; ++c){
    if (c < 14){
      stage4(Wt_hd3, c + 2, c & 3);
      __builtin_amdgcn_sched_barrier(0);
    }
    if (c < 15 && nq == ((c + 1) >> 2)){
      #pragma unroll
      for (int q = 0; q < 4; ++q)
        *(short8*)(LT + HXo + ((c + 1) & 1) * 8192 + rh * 4096 + (q * 64 + m * 4 + g) * 16)
          = p[q][(c + 1) & 3];
    }
    const char* hxb = LT + HXo + (c & 1) * 8192 + rh * 4096 + (m * 4 + g) * 16;
    short8 bh[4];
    #pragma unroll
    for (int q = 0; q < 4; ++q) bh[q] = *(const short8*)(hxb + q * 1024);
    const char* wb = LT + ((c + 2) & 3) * 32768 + nq * 8192 + afoff;
    #pragma unroll
    for (int of = 0; of < 8; ++of){
      short8 aw = *(const short8*)(wb + of * 1024);
      #pragma unroll
      for (int q = 0; q < 4; ++q)
        acc[q][of] = __builtin_amdgcn_mfma_f32_16x16x32_bf16(aw, bh[q], acc[q][of], 0, 0, 0);
    }
    if (c < 14)       CBAR(4);
    else if (c == 14) CBAR(0);
  }

  // epilogue: +bias, store
  #pragma unroll
  for (int q = 0; q < 4; ++q)
    #pragma unroll
    for (int of = 0; of < 8; ++of){
      f32x4 bhd = *(const f32x4*)(b_head + nq * 128 + of * 16 + g * 4);
      f32x4 v;
      #pragma unroll
      for (int r = 0; r < 4; ++r) v[r] = acc[q][of][r] + bhd[r];
      *(f32x4*)(out + (rowbase + q * 16 + m) * 512 + nq * 128 + of * 16 + g * 4) = v;
    }
}

// ---------------------------------------------------------------------------
extern "C" void kernel_launch(void* const* d_in, const int* in_sizes, int n_in,
                              void* d_out, int out_size, void* d_ws, size_t ws_size,
                              hipStream_t stream)
{
  const float* x      = (const float*)d_in[0];
  const float* W_in   = (const float*)d_in[1];
  const float* b_in   = (const float*)d_in[2];
  const float* ln_g   = (const float*)d_in[3];
  const float* ln_b   = (const float*)d_in[4];
  const float* W1     = (const float*)d_in[5];
  const float* b1     = (const float*)d_in[6];
  const float* W2     = (const float*)d_in[7];
  const float* b2     = (const float*)d_in[8];
  const float* W_head = (const float*)d_in[9];
  const float* b_head = (const float*)d_in[10];
  float* out = (float*)d_out;
  const int B = in_sizes[0] / 512;

  char* ws = (char*)d_ws;
  u16*   Wt_in3 = (u16*)ws;                 // 262144
  u16*   Wt_hd3 = Wt_in3 + 262144;          // 262144
  u16*   gw1f   = Wt_hd3 + 262144;          // 20480
  u16*   updA   = gw1f + 20480;             // 32768
  float* Up     = (float*)(updA + 32768);   // 32
  float* Vp     = Up + 32;                  // 32

  prep_k<<<2256, 256, 0, stream>>>(W_in, W_head, ln_g, W1, W2, b2, Wt_in3, Wt_hd3, gw1f, updA);
  uv_k<<<32, 64, 0, stream>>>(ln_g, ln_b, W1, b1, Up, Vp);
  fused_k<<<B / 128, 512, 0, stream>>>(x, Wt_in3, b_in, Wt_hd3, b_head, gw1f, updA, Up, Vp, out);
}